// Round 1
// baseline (473.316 us; speedup 1.0000x reference)
//
#include <hip/hip_runtime.h>
#include <hip/hip_bf16.h>

#define NP    4096
#define DFEAT 512
#define NHEAD 8
#define DHEAD 64
#define WINSZ 64
#define PAD   8   // LDS padding (elements) to rotate banks across rows

using bf16x8 = __attribute__((ext_vector_type(8))) short;
using f32x4  = __attribute__((ext_vector_type(4))) float;

__device__ __forceinline__ f32x4 mfma16(bf16x8 a, bf16x8 b, f32x4 c) {
    return __builtin_amdgcn_mfma_f32_16x16x32_bf16(a, b, c, 0, 0, 0);
}
__device__ __forceinline__ f32x4 zero4() { f32x4 z = {0.f, 0.f, 0.f, 0.f}; return z; }

__global__ void convert_weights(const float* __restrict__ wqkv,
                                const float* __restrict__ projw,
                                __hip_bfloat16* __restrict__ wq_bf,
                                __hip_bfloat16* __restrict__ pw_bf) {
    int i = blockIdx.x * blockDim.x + threadIdx.x;
    const int NQ  = 3 * DFEAT * DFEAT;   // 786432
    const int NPW = DFEAT * DFEAT;       // 262144
    if (i < NQ) wq_bf[i] = __float2bfloat16(wqkv[i]);
    else { int j = i - NQ; if (j < NPW) pw_bf[j] = __float2bfloat16(projw[j]); }
}

__launch_bounds__(512, 2)
__global__ void seqwin_attn(const float* __restrict__ x,
                            const __hip_bfloat16* __restrict__ wq_bf,
                            const __hip_bfloat16* __restrict__ pw_bf,
                            const float* __restrict__ proj_b,
                            float* __restrict__ out) {
    __shared__ __hip_bfloat16 xs [64][DFEAT + PAD];   // x tile, bf16      (~65 KB)
    __shared__ __hip_bfloat16 Qs [64][DHEAD + PAD];   // [q_tok][dh]       (~9 KB)
    __shared__ __hip_bfloat16 Ks [64][DHEAD + PAD];   // [k_tok][dh]
    __shared__ __hip_bfloat16 Vts[64][DHEAD + PAD];   // [dh][k_tok]  (transposed)
    __shared__ __hip_bfloat16 Ps [64][DHEAD + PAD];   // [q_tok][k_tok]
    __shared__ __hip_bfloat16 Ohs[64][DHEAD + PAD];   // [q_tok][dh]

    const int tid  = threadIdx.x;
    const int wid  = tid >> 6;      // 0..7
    const int lane = tid & 63;
    const int ln16 = lane & 15;
    const int lg   = lane >> 4;     // 0..3

    const int bw = blockIdx.x;
    const int b  = bw >> 6;
    const int w  = bw & 63;
    const size_t xbase = ((size_t)b * NP + (size_t)w * WINSZ) * DFEAT;

    // ---- stage x tile -> bf16 LDS (64 x 512), coalesced float4 loads ----
    #pragma unroll
    for (int it = 0; it < 16; ++it) {
        int f   = it * 512 + tid;    // float4 index, 128 per row
        int row = f >> 7;
        int c4  = f & 127;
        float4 v = *(const float4*)(x + xbase + (size_t)row * DFEAT + (size_t)c4 * 4);
        __hip_bfloat16* p = &xs[row][c4 * 4];
        p[0] = __float2bfloat16(v.x);
        p[1] = __float2bfloat16(v.y);
        p[2] = __float2bfloat16(v.z);
        p[3] = __float2bfloat16(v.w);
    }
    __syncthreads();

    f32x4 oacc[4][4];   // persistent: rows rt*16.., cols wid*64 + ct*16..
    #pragma unroll
    for (int i = 0; i < 4; ++i)
        #pragma unroll
        for (int j = 0; j < 4; ++j) oacc[i][j] = zero4();

    for (int h = 0; h < NHEAD; ++h) {
        // ---- QKV GEMM: 12 col-tiles (3 mats x 4 tiles of 16) over 8 waves ----
        for (int ct = wid; ct < 12; ct += 8) {
            int t  = ct >> 2;          // 0=Q 1=K 2=V
            int n0 = (ct & 3) << 4;
            const __hip_bfloat16* wrow =
                wq_bf + ((size_t)(t * DFEAT + h * DHEAD + n0 + ln16)) * DFEAT;
            f32x4 acc[4];
            #pragma unroll
            for (int rt = 0; rt < 4; ++rt) acc[rt] = zero4();
            for (int ks = 0; ks < 16; ++ks) {
                int k0 = ks * 32 + lg * 8;
                bf16x8 bfr = *(const bf16x8*)(wrow + k0);
                #pragma unroll
                for (int rt = 0; rt < 4; ++rt) {
                    bf16x8 afr = *(const bf16x8*)&xs[rt * 16 + ln16][k0];
                    acc[rt] = mfma16(afr, bfr, acc[rt]);
                }
            }
            #pragma unroll
            for (int rt = 0; rt < 4; ++rt)
                #pragma unroll
                for (int j = 0; j < 4; ++j) {
                    int tok = rt * 16 + lg * 4 + j;
                    int d   = n0 + ln16;
                    __hip_bfloat16 val = __float2bfloat16(acc[rt][j]);
                    if (t == 0)      Qs[tok][d]  = val;
                    else if (t == 1) Ks[tok][d]  = val;
                    else             Vts[d][tok] = val;
                }
        }
        __syncthreads();

        // ---- S = scale * Q K^T ; softmax ; P (waves 0..3, 16 q-rows each) ----
        if (wid < 4) {
            f32x4 s[4];
            #pragma unroll
            for (int ct = 0; ct < 4; ++ct) s[ct] = zero4();
            #pragma unroll
            for (int ks = 0; ks < 2; ++ks) {
                int k0 = ks * 32 + lg * 8;
                bf16x8 afr = *(const bf16x8*)&Qs[wid * 16 + ln16][k0];
                #pragma unroll
                for (int ct = 0; ct < 4; ++ct) {
                    bf16x8 bfr = *(const bf16x8*)&Ks[ct * 16 + ln16][k0];
                    s[ct] = mfma16(afr, bfr, s[ct]);
                }
            }
            const float scale = 0.125f;   // DH^-0.5
            #pragma unroll
            for (int j = 0; j < 4; ++j) {
                float sv[4];
                float m = -1e30f;
                #pragma unroll
                for (int ct = 0; ct < 4; ++ct) { sv[ct] = s[ct][j] * scale; m = fmaxf(m, sv[ct]); }
                #pragma unroll
                for (int off = 1; off < 16; off <<= 1) m = fmaxf(m, __shfl_xor(m, off));
                float pv[4], sum = 0.f;
                #pragma unroll
                for (int ct = 0; ct < 4; ++ct) { pv[ct] = __expf(sv[ct] - m); sum += pv[ct]; }
                #pragma unroll
                for (int off = 1; off < 16; off <<= 1) sum += __shfl_xor(sum, off);
                float inv = 1.f / sum;
                int q = wid * 16 + lg * 4 + j;
                #pragma unroll
                for (int ct = 0; ct < 4; ++ct)
                    Ps[q][ct * 16 + ln16] = __float2bfloat16(pv[ct] * inv);
            }
        }
        __syncthreads();

        // ---- O = P V (waves 0..3) ----
        if (wid < 4) {
            f32x4 o[4];
            #pragma unroll
            for (int ct = 0; ct < 4; ++ct) o[ct] = zero4();
            #pragma unroll
            for (int ks = 0; ks < 2; ++ks) {
                int k0 = ks * 32 + lg * 8;
                bf16x8 afr = *(const bf16x8*)&Ps[wid * 16 + ln16][k0];
                #pragma unroll
                for (int ct = 0; ct < 4; ++ct) {
                    bf16x8 bfr = *(const bf16x8*)&Vts[ct * 16 + ln16][k0];
                    o[ct] = mfma16(afr, bfr, o[ct]);
                }
            }
            #pragma unroll
            for (int ct = 0; ct < 4; ++ct)
                #pragma unroll
                for (int j = 0; j < 4; ++j)
                    Ohs[wid * 16 + lg * 4 + j][ct * 16 + ln16] = __float2bfloat16(o[ct][j]);
        }
        __syncthreads();

        // ---- out_acc += Oh @ projW^T slice (all 8 waves; wave owns 64 cols) ----
        #pragma unroll
        for (int ks = 0; ks < 2; ++ks) {
            int k0 = ks * 32 + lg * 8;
            bf16x8 a[4];
            #pragma unroll
            for (int rt = 0; rt < 4; ++rt) a[rt] = *(const bf16x8*)&Ohs[rt * 16 + ln16][k0];
            #pragma unroll
            for (int ct = 0; ct < 4; ++ct) {
                const __hip_bfloat16* prow =
                    pw_bf + ((size_t)(wid * 64 + ct * 16 + ln16)) * DFEAT + h * DHEAD + k0;
                bf16x8 bfr = *(const bf16x8*)prow;
                #pragma unroll
                for (int rt = 0; rt < 4; ++rt)
                    oacc[rt][ct] = mfma16(a[rt], bfr, oacc[rt][ct]);
            }
        }
        // no barrier needed here: next QKV writes Qs/Ks/Vts (disjoint from Ohs/pw reads);
        // the barrier after next QKV orders proj(h) before S(h+1)'s Ps writes.
    }

    // ---- epilogue: bias + fp32 store ----
    #pragma unroll
    for (int rt = 0; rt < 4; ++rt)
        #pragma unroll
        for (int ct = 0; ct < 4; ++ct) {
            int col = wid * 64 + ct * 16 + ln16;
            float bias = proj_b[col];
            #pragma unroll
            for (int j = 0; j < 4; ++j) {
                int tok = rt * 16 + lg * 4 + j;
                out[((size_t)b * NP + (size_t)w * WINSZ + tok) * DFEAT + col] =
                    oacc[rt][ct][j] + bias;
            }
        }
}

extern "C" void kernel_launch(void* const* d_in, const int* in_sizes, int n_in,
                              void* d_out, int out_size, void* d_ws, size_t ws_size,
                              hipStream_t stream) {
    const float* x      = (const float*)d_in[0];
    // d_in[1] (z) is unused by the reference
    const float* w_qkv  = (const float*)d_in[2];
    const float* proj_w = (const float*)d_in[3];
    const float* proj_b = (const float*)d_in[4];
    float* outp = (float*)d_out;

    __hip_bfloat16* wq_bf = (__hip_bfloat16*)d_ws;                 // 786432 * 2B
    __hip_bfloat16* pw_bf = wq_bf + 3 * DFEAT * DFEAT;             // 262144 * 2B

    // 1,048,576 total weight elements, one thread each
    convert_weights<<<2048, 512, 0, stream>>>(w_qkv, proj_w, wq_bf, pw_bf);

    seqwin_attn<<<512, 512, 0, stream>>>(x, wq_bf, pw_bf, proj_b, outp);
}

// Round 2
// 174.758 us; speedup vs baseline: 2.7084x; 2.7084x over previous
//
#include <hip/hip_runtime.h>
#include <hip/hip_bf16.h>

#define NP    4096
#define DFEAT 512
#define NHEAD 8
#define DHEAD 64
#define WINSZ 64
#define PAD   8     // xs row padding (elements)
#define LDSH  72    // DHEAD + 8 pad

using bf16x8 = __attribute__((ext_vector_type(8))) short;
using f32x4  = __attribute__((ext_vector_type(4))) float;

__device__ __forceinline__ f32x4 mfma16(bf16x8 a, bf16x8 b, f32x4 c) {
    return __builtin_amdgcn_mfma_f32_16x16x32_bf16(a, b, c, 0, 0, 0);
}
__device__ __forceinline__ f32x4 zero4() { f32x4 z = {0.f, 0.f, 0.f, 0.f}; return z; }

__global__ void convert_weights(const float* __restrict__ wqkv,
                                const float* __restrict__ projw,
                                __hip_bfloat16* __restrict__ wq_bf,
                                __hip_bfloat16* __restrict__ pw_bf) {
    int i = blockIdx.x * blockDim.x + threadIdx.x;
    const int NQ  = 3 * DFEAT * DFEAT;   // 786432
    const int NPW = DFEAT * DFEAT;       // 262144
    if (i < NQ) wq_bf[i] = __float2bfloat16(wqkv[i]);
    else { int j = i - NQ; if (j < NPW) pw_bf[j] = __float2bfloat16(projw[j]); }
}

__launch_bounds__(512, 1)
__global__ void seqwin_attn(const float* __restrict__ x,
                            const __hip_bfloat16* __restrict__ wq_bf,
                            const __hip_bfloat16* __restrict__ pw_bf,
                            const float* __restrict__ proj_b,
                            float* __restrict__ out) {
    __shared__ __hip_bfloat16 xs  [64][DFEAT + PAD];  // x tile bf16 (~65 KB)
    __shared__ __hip_bfloat16 bufQ[2][64][LDSH];      // Q, then P   (per head of pair)
    __shared__ __hip_bfloat16 bufK[2][64][LDSH];      // K, then Oh
    __shared__ __hip_bfloat16 bufV[2][64][LDSH];      // V^T [dh][tok]

    const int tid  = threadIdx.x;
    const int wid  = tid >> 6;      // 0..7
    const int lane = tid & 63;
    const int ln16 = lane & 15;
    const int lg   = lane >> 4;     // 0..3
    const int hq   = wid >> 2;      // which head of the pair this wave serves
    const int wq   = wid & 3;       // wave id within the head-quad

    const int bw = blockIdx.x;
    const int b  = bw >> 6;
    const int w  = bw & 63;
    const size_t xbase = ((size_t)b * NP + (size_t)w * WINSZ) * DFEAT;

    // ---- stage x tile -> bf16 LDS (64 x 512), coalesced float4 loads ----
    #pragma unroll
    for (int it = 0; it < 16; ++it) {
        int f   = it * 512 + tid;    // float4 index, 128 per row
        int row = f >> 7;
        int c4  = f & 127;
        float4 v = *(const float4*)(x + xbase + (size_t)row * DFEAT + (size_t)c4 * 4);
        __hip_bfloat16* p = &xs[row][c4 * 4];
        p[0] = __float2bfloat16(v.x);
        p[1] = __float2bfloat16(v.y);
        p[2] = __float2bfloat16(v.z);
        p[3] = __float2bfloat16(v.w);
    }
    __syncthreads();

    f32x4 oacc[4][4];   // rows rt*16.., cols wid*64 + ct*16..  (64 VGPRs, persistent)
    #pragma unroll
    for (int i = 0; i < 4; ++i)
        #pragma unroll
        for (int j = 0; j < 4; ++j) oacc[i][j] = zero4();

    for (int hp = 0; hp < 4; ++hp) {
        const int h0 = hp * 2;

        // ---- phase 1: QKV GEMM for the head pair: 24 col-tiles over 8 waves ----
        #pragma unroll
        for (int i = 0; i < 3; ++i) {
            int ct2 = wid + 8 * i;          // 0..23, each exactly once
            int hh  = ct2 / 12;             // head within pair
            int rem = ct2 - hh * 12;
            int t   = rem >> 2;             // 0=Q 1=K 2=V
            int n0  = (rem & 3) << 4;
            const __hip_bfloat16* wrow =
                wq_bf + ((size_t)(t * DFEAT + (h0 + hh) * DHEAD + n0 + ln16)) * DFEAT;
            f32x4 acc[4];
            #pragma unroll
            for (int rt = 0; rt < 4; ++rt) acc[rt] = zero4();
            for (int ks = 0; ks < 16; ++ks) {
                int k0 = ks * 32 + lg * 8;
                bf16x8 bfr = *(const bf16x8*)(wrow + k0);
                #pragma unroll
                for (int rt = 0; rt < 4; ++rt) {
                    bf16x8 afr = *(const bf16x8*)&xs[rt * 16 + ln16][k0];
                    acc[rt] = mfma16(afr, bfr, acc[rt]);
                }
            }
            #pragma unroll
            for (int rt = 0; rt < 4; ++rt)
                #pragma unroll
                for (int j = 0; j < 4; ++j) {
                    int tok = rt * 16 + lg * 4 + j;
                    int d   = n0 + ln16;
                    __hip_bfloat16 val = __float2bfloat16(acc[rt][j]);
                    if (t == 0)      bufQ[hh][tok][d]   = val;
                    else if (t == 1) bufK[hh][tok][d]   = val;
                    else             bufV[hh][d][tok]   = val;
                }
        }
        __syncthreads();

        // ---- phase 2: S = scale*Q K^T ; softmax ; P -> bufQ (all 8 waves) ----
        {
            f32x4 s[4];
            #pragma unroll
            for (int ct = 0; ct < 4; ++ct) s[ct] = zero4();
            #pragma unroll
            for (int ks = 0; ks < 2; ++ks) {
                int k0 = ks * 32 + lg * 8;
                bf16x8 afr = *(const bf16x8*)&bufQ[hq][wq * 16 + ln16][k0];
                #pragma unroll
                for (int ct = 0; ct < 4; ++ct) {
                    bf16x8 bfr = *(const bf16x8*)&bufK[hq][ct * 16 + ln16][k0];
                    s[ct] = mfma16(afr, bfr, s[ct]);
                }
            }
            const float scale = 0.125f;   // DH^-0.5
            #pragma unroll
            for (int j = 0; j < 4; ++j) {
                float sv[4];
                float m = -1e30f;
                #pragma unroll
                for (int ct = 0; ct < 4; ++ct) { sv[ct] = s[ct][j] * scale; m = fmaxf(m, sv[ct]); }
                #pragma unroll
                for (int off = 1; off < 16; off <<= 1) m = fmaxf(m, __shfl_xor(m, off));
                float pv[4], sum = 0.f;
                #pragma unroll
                for (int ct = 0; ct < 4; ++ct) { pv[ct] = __expf(sv[ct] - m); sum += pv[ct]; }
                #pragma unroll
                for (int off = 1; off < 16; off <<= 1) sum += __shfl_xor(sum, off);
                float inv = 1.f / sum;
                int q = wq * 16 + lg * 4 + j;
                #pragma unroll
                for (int ct = 0; ct < 4; ++ct)
                    bufQ[hq][q][ct * 16 + ln16] = __float2bfloat16(pv[ct] * inv);
            }
        }
        __syncthreads();

        // ---- phase 3: O = P V -> bufK (all 8 waves) ----
        {
            f32x4 o[4];
            #pragma unroll
            for (int ct = 0; ct < 4; ++ct) o[ct] = zero4();
            #pragma unroll
            for (int ks = 0; ks < 2; ++ks) {
                int k0 = ks * 32 + lg * 8;
                bf16x8 afr = *(const bf16x8*)&bufQ[hq][wq * 16 + ln16][k0];   // P
                #pragma unroll
                for (int ct = 0; ct < 4; ++ct) {
                    bf16x8 bfr = *(const bf16x8*)&bufV[hq][ct * 16 + ln16][k0];
                    o[ct] = mfma16(afr, bfr, o[ct]);
                }
            }
            #pragma unroll
            for (int ct = 0; ct < 4; ++ct)
                #pragma unroll
                for (int j = 0; j < 4; ++j)
                    bufK[hq][wq * 16 + lg * 4 + j][ct * 16 + ln16] = __float2bfloat16(o[ct][j]);
        }
        __syncthreads();

        // ---- phase 4: oacc += Oh @ projW^T slice, both heads (all 8 waves) ----
        #pragma unroll
        for (int hh = 0; hh < 2; ++hh) {
            #pragma unroll
            for (int ks = 0; ks < 2; ++ks) {
                int k0 = ks * 32 + lg * 8;
                bf16x8 a[4];
                #pragma unroll
                for (int rt = 0; rt < 4; ++rt)
                    a[rt] = *(const bf16x8*)&bufK[hh][rt * 16 + ln16][k0];
                #pragma unroll
                for (int ct = 0; ct < 4; ++ct) {
                    const __hip_bfloat16* prow =
                        pw_bf + ((size_t)(wid * 64 + ct * 16 + ln16)) * DFEAT
                              + (h0 + hh) * DHEAD + k0;
                    bf16x8 bfr = *(const bf16x8*)prow;
                    #pragma unroll
                    for (int rt = 0; rt < 4; ++rt)
                        oacc[rt][ct] = mfma16(a[rt], bfr, oacc[rt][ct]);
                }
            }
        }
        __syncthreads();   // protect bufK/bufQ/bufV before next pair's phase 1
    }

    // ---- epilogue: bias + fp32 store ----
    #pragma unroll
    for (int rt = 0; rt < 4; ++rt)
        #pragma unroll
        for (int ct = 0; ct < 4; ++ct) {
            int col = wid * 64 + ct * 16 + ln16;
            float bias = proj_b[col];
            #pragma unroll
            for (int j = 0; j < 4; ++j) {
                int tok = rt * 16 + lg * 4 + j;
                out[((size_t)b * NP + (size_t)w * WINSZ + tok) * DFEAT + col] =
                    oacc[rt][ct][j] + bias;
            }
        }
}

extern "C" void kernel_launch(void* const* d_in, const int* in_sizes, int n_in,
                              void* d_out, int out_size, void* d_ws, size_t ws_size,
                              hipStream_t stream) {
    const float* x      = (const float*)d_in[0];
    // d_in[1] (z) is unused by the reference
    const float* w_qkv  = (const float*)d_in[2];
    const float* proj_w = (const float*)d_in[3];
    const float* proj_b = (const float*)d_in[4];
    float* outp = (float*)d_out;

    __hip_bfloat16* wq_bf = (__hip_bfloat16*)d_ws;                 // 786432 * 2B
    __hip_bfloat16* pw_bf = wq_bf + 3 * DFEAT * DFEAT;             // 262144 * 2B

    convert_weights<<<2048, 512, 0, stream>>>(w_qkv, proj_w, wq_bf, pw_bf);

    seqwin_attn<<<512, 512, 0, stream>>>(x, wq_bf, pw_bf, proj_b, outp);
}